// Round 1
// baseline (769.772 us; speedup 1.0000x reference)
//
#include <hip/hip_runtime.h>
#include <hip/hip_fp16.h>

constexpr int IN_DIM  = 256;
constexpr int HID_DIM = 128;
constexpr int OUT_DIM = 64;

constexpr int NPB_SHIFT = 8;          // 256 nodes per bucket
constexpr int NPB   = 1 << NPB_SHIFT;
constexpr int NBMAX = 512;            // max buckets supported in LDS tables
constexpr int CHUNK = 4096;           // edges per binning block
constexpr int CAP_B = 12288;          // LDS col-stage capacity (48 KB)

typedef _Float16 half8 __attribute__((ext_vector_type(8)));
typedef float floatx4 __attribute__((ext_vector_type(4)));

// ---------------- misc ----------------

__global__ __launch_bounds__(256) void k_zero(int* __restrict__ p, int n) {
  int i = blockIdx.x * 256 + threadIdx.x;
  if (i < n) p[i] = 0;
}

// ---------------- CSR build via bucketed counting sort ----------------

__global__ __launch_bounds__(256) void k_hist(const int* __restrict__ dst, int E, int NB,
                                              int* __restrict__ bsize) {
  __shared__ int h[NBMAX];
  for (int i = threadIdx.x; i < NB; i += 256) h[i] = 0;
  __syncthreads();
  int e0 = blockIdx.x * CHUNK;
  int e1 = min(e0 + CHUNK, E);
  for (int e = e0 + threadIdx.x; e < e1; e += 256) {
    int d = __builtin_nontemporal_load(&dst[e]);
    atomicAdd(&h[d >> NPB_SHIFT], 1);
  }
  __syncthreads();
  for (int b = threadIdx.x; b < NB; b += 256) {
    int c = h[b];
    if (c) atomicAdd(&bsize[b], c);
  }
}

__global__ __launch_bounds__(512) void k_scanb(const int* __restrict__ bsize, int NB, int E,
                                               int* __restrict__ boff, int* __restrict__ gcur) {
  __shared__ int sh[NBMAX + 1];
  for (int i = threadIdx.x; i < NB; i += 512) sh[i] = bsize[i];
  __syncthreads();
  if (threadIdx.x == 0) {
    int run = 0;
    for (int b = 0; b < NB; b++) { int v = sh[b]; sh[b] = run; run += v; }
    sh[NB] = run;
  }
  __syncthreads();
  for (int i = threadIdx.x; i < NB; i += 512) { boff[i] = sh[i]; gcur[i] = sh[i]; }
  if (threadIdx.x == 0) boff[NB] = sh[NB];
}

__global__ __launch_bounds__(256) void k_binA(const int* __restrict__ src,
                                              const int* __restrict__ dst, int E, int NB,
                                              int* __restrict__ gcur,
                                              unsigned long long* __restrict__ bin) {
  __shared__ unsigned long long sbuf[CHUNK];  // 32 KB
  __shared__ int h[NBMAX], lofs[NBMAX], wofs[NBMAX], hcur[NBMAX];
  for (int i = threadIdx.x; i < NB; i += 256) h[i] = 0;
  __syncthreads();
  int e0 = blockIdx.x * CHUNK;
  int e1 = min(e0 + CHUNK, E);
  for (int e = e0 + threadIdx.x; e < e1; e += 256) {
    int d = __builtin_nontemporal_load(&dst[e]);
    atomicAdd(&h[d >> NPB_SHIFT], 1);
  }
  __syncthreads();
  for (int b = threadIdx.x; b < NB; b += 256) {
    int c = h[b];
    if (c) wofs[b] = atomicAdd(&gcur[b], c);
  }
  if (threadIdx.x == 0) {
    int run = 0;
    for (int b = 0; b < NB; b++) { lofs[b] = run; run += h[b]; }
  }
  __syncthreads();
  for (int b = threadIdx.x; b < NB; b += 256) hcur[b] = lofs[b];
  __syncthreads();
  for (int e = e0 + threadIdx.x; e < e1; e += 256) {
    int d = dst[e];
    int s = src[e];
    int b = d >> NPB_SHIFT;
    int p = atomicAdd(&hcur[b], 1);
    sbuf[p] = ((unsigned long long)(unsigned)d << 32) | (unsigned)s;
  }
  __syncthreads();
  int total = e1 - e0;
  for (int i = threadIdx.x; i < total; i += 256) {
    unsigned long long v = sbuf[i];
    int b = (int)(v >> 32) >> NPB_SHIFT;
    bin[(size_t)wofs[b] + (i - lofs[b])] = v;
  }
}

__global__ __launch_bounds__(256) void k_passB(const unsigned long long* __restrict__ bin,
                                               const int* __restrict__ boff, int NB, int N, int E,
                                               int* __restrict__ rowptr, float* __restrict__ dis,
                                               int* __restrict__ col) {
  __shared__ unsigned int colbuf[CAP_B];  // 48 KB
  __shared__ int lcnt[NPB], lofs2[NPB + 1], lpos[NPB];
  int b = blockIdx.x;
  int lo = b << NPB_SHIFT;
  int e0 = boff[b], e1 = boff[b + 1];
  int tot = e1 - e0;
  if (threadIdx.x < NPB) lcnt[threadIdx.x] = 0;
  __syncthreads();
  for (int i = threadIdx.x; i < tot; i += 256) {
    unsigned long long v = bin[(size_t)e0 + i];
    atomicAdd(&lcnt[(int)(v >> 32) & (NPB - 1)], 1);
  }
  __syncthreads();
  if (threadIdx.x == 0) {
    int run = 0;
    for (int i = 0; i < NPB; i++) { lofs2[i] = run; run += lcnt[i]; }
    lofs2[NPB] = run;
  }
  __syncthreads();
  if (threadIdx.x < NPB) {
    int node = lo + threadIdx.x;
    if (node < N) {
      rowptr[node] = e0 + lofs2[threadIdx.x];
      dis[node] = rsqrtf((float)lcnt[threadIdx.x] + 1.0f);  // +1 self loop
    }
    lpos[threadIdx.x] = lofs2[threadIdx.x];
  }
  __syncthreads();
  for (int i = threadIdx.x; i < tot; i += 256) {
    unsigned long long v = bin[(size_t)e0 + i];
    int idx = (int)(v >> 32) & (NPB - 1);
    int p = atomicAdd(&lpos[idx], 1);
    unsigned int s = (unsigned int)v;
    if (p < CAP_B) colbuf[p] = s;
    else col[(size_t)e0 + p] = s;
  }
  __syncthreads();
  int cp = min(tot, CAP_B);
  for (int i = threadIdx.x; i < cp; i += 256)
    __builtin_nontemporal_store(colbuf[i], (unsigned int*)&col[(size_t)e0 + i]);
  if (b == 0 && threadIdx.x == 0) rowptr[N] = E;
}

// ---------------- W pre-pack into MFMA B-fragment order (fp16) ----------------
// B-frag for 16x16x32_f16: lane holds B[k = (lane>>4)*8 + j][n = lane&15].
// Wp flat index: ((ct*(K/32) + ks)*64 + lane)*8 + j, ct = n>>4, ks = k>>5.

template <int K, int N>
__global__ __launch_bounds__(256) void k_packW(const float* __restrict__ W,
                                               _Float16* __restrict__ Wp) {
  int idx = blockIdx.x * 256 + threadIdx.x;
  if (idx >= K * N) return;
  int k = idx / N, n = idx % N;
  int ct = n >> 4, ks = k >> 5, q = (k >> 3) & 3, j = k & 7;
  int lane = (n & 15) + (q << 4);
  Wp[((((size_t)ct * (K / 32) + ks) * 64 + lane) << 3) + j] = (_Float16)W[idx];
}

// ---------------- MFMA GEMM: out[r][c] = fp16(dis[r] * sum_k A[r][k]*W[k][c]) --------
// No LDS. Block = 4 waves; wave w computes rows [blk*64 + w*16, +16) x all N cols.

template <int K, int N, typename AT>
__global__ __launch_bounds__(256) void k_gemm_mfma(const AT* __restrict__ A,
                                                   const _Float16* __restrict__ Wp,
                                                   const float* __restrict__ dis,
                                                   __half* __restrict__ out, int M) {
  constexpr int CT = N / 16;   // 16-col tiles
  constexpr int KS = K / 32;   // 32-k steps
  const int wave = threadIdx.x >> 6, lane = threadIdx.x & 63;
  const int q = lane >> 4, mlane = lane & 15;
  const int row0 = blockIdx.x * 64 + wave * 16;
  int arow = row0 + mlane;
  if (arow > M - 1) arow = M - 1;  // clamp (dup row, stores guarded)

  floatx4 acc[CT];
#pragma unroll
  for (int c = 0; c < CT; c++) acc[c] = (floatx4){0.f, 0.f, 0.f, 0.f};

#pragma unroll
  for (int ks = 0; ks < KS; ks++) {
    half8 a;
    if constexpr (sizeof(AT) == 4) {
      const float* ap = &A[(size_t)arow * K + ks * 32 + q * 8];
      float4 f0 = *(const float4*)ap;
      float4 f1 = *(const float4*)(ap + 4);
      a[0] = (_Float16)f0.x; a[1] = (_Float16)f0.y;
      a[2] = (_Float16)f0.z; a[3] = (_Float16)f0.w;
      a[4] = (_Float16)f1.x; a[5] = (_Float16)f1.y;
      a[6] = (_Float16)f1.z; a[7] = (_Float16)f1.w;
    } else {
      a = *(const half8*)&A[(size_t)arow * K + ks * 32 + q * 8];
    }
#pragma unroll
    for (int c = 0; c < CT; c++) {
      half8 b = *(const half8*)&Wp[((((size_t)c * KS) + ks) * 64 + lane) << 3];
      acc[c] = __builtin_amdgcn_mfma_f32_16x16x32_f16(a, b, acc[c], 0, 0, 0);
    }
  }

  // C/D layout: col = lane&15 (+ct*16), row = q*4 + r
  float dv[4]; int orow[4];
#pragma unroll
  for (int r = 0; r < 4; r++) {
    orow[r] = row0 + q * 4 + r;
    dv[r] = (orow[r] < M) ? dis[orow[r]] : 0.f;
  }
#pragma unroll
  for (int c = 0; c < CT; c++) {
    int cl = c * 16 + mlane;
#pragma unroll
    for (int r = 0; r < 4; r++)
      if (orow[r] < M)
        out[(size_t)orow[r] * N + cl] = __float2half_rn(dv[r] * acc[c][r]);
  }
}

// ---------------- aggregation: out[v] = act(dv*(g[v] + sum_u g[u]) + b) ----------------
// one wave per node; g fp16; fp32 accumulate. Explicitly software-pipelined:
// double-buffered 8-deep chunks so next chunk's col loads + gathers are in
// flight while the current chunk is accumulated (compiler emits partial
// vmcnt waits instead of full drains -> ~2x memory-level parallelism).
// F==64: two neighbors per load instruction (lane halves), shfl_xor combine.

template <int F, bool RELU, typename HOUT>
__global__ __launch_bounds__(256) void k_agg(const __half* __restrict__ g,
                                             const int* __restrict__ rowptr,
                                             const int* __restrict__ col,
                                             const float* __restrict__ dis,
                                             const float* __restrict__ bias,
                                             HOUT* __restrict__ out, int n) {
  const int lane = threadIdx.x & 63;
  const int v = blockIdx.x * 4 + (threadIdx.x >> 6);
  if (v >= n) return;
  int p = rowptr[v], end = rowptr[v + 1];
  const float dv = dis[v];
  const __half2* __restrict__ gp = (const __half2*)g;

  if constexpr (F == 128) {
    // lane covers dims [2*lane, 2*lane+1]; row stride = 64 half2
    float2 s0 = __half22float2(gp[(size_t)v * 64 + lane]);
    float axA = s0.x, ayA = s0.y, axB = 0.f, ayB = 0.f;
    __half2 tA[8], tB[8];

    auto LG = [&](__half2* tt, int q) {
#pragma unroll
      for (int j = 0; j < 8; j++) {
        int u = __builtin_nontemporal_load(&col[q + j]);
        tt[j] = gp[(size_t)u * 64 + lane];
      }
    };
    auto ACC = [&](const __half2* tt, float& sx, float& sy) {
#pragma unroll
      for (int j = 0; j < 8; j++) {
        float2 f = __half22float2(tt[j]);
        sx += f.x; sy += f.y;
      }
    };

    int rem = end - p;
    bool haveA = false;
    if (rem >= 8) { LG(tA, p); p += 8; rem -= 8; haveA = true; }
    while (rem >= 16) {
      LG(tB, p); ACC(tA, axA, ayA); p += 8; rem -= 8;
      LG(tA, p); ACC(tB, axB, ayB); p += 8; rem -= 8;
    }
    if (haveA) {
      if (rem >= 8) {
        LG(tB, p); ACC(tA, axA, ayA); p += 8; rem -= 8;
        ACC(tB, axB, ayB);
      } else {
        ACC(tA, axA, ayA);
      }
    }
    for (; rem > 0; rem--, p++) {
      int u = __builtin_nontemporal_load(&col[p]);
      float2 f = __half22float2(gp[(size_t)u * 64 + lane]);
      axA += f.x; ayA += f.y;
    }

    float ox = fmaf(dv, axA + axB, bias[lane * 2]);
    float oy = fmaf(dv, ayA + ayB, bias[lane * 2 + 1]);
    if (RELU) { ox = fmaxf(ox, 0.f); oy = fmaxf(oy, 0.f); }
    if constexpr (sizeof(HOUT) == 2) {
      *(__half2*)&out[(size_t)v * 128 + lane * 2] = __float22half2_rn(make_float2(ox, oy));
    } else {
      float2 o; o.x = ox; o.y = oy;
      *(float2*)&out[(size_t)v * 128 + lane * 2] = o;
    }
  } else {
    // F == 64: lanes 0..31 take even neighbor of each pair, lanes 32..63 odd.
    // Each lane covers dims [2*dl, 2*dl+1]; row stride = 32 half2.
    const int half = lane >> 5, dl = lane & 31;
    float axA = 0.f, ayA = 0.f, axB = 0.f, ayB = 0.f;
    if (half == 0) {
      float2 f = __half22float2(gp[(size_t)v * 32 + dl]);
      axA = f.x; ayA = f.y;  // self term, counted once
    }
    __half2 tA[8], tB[8];

    auto LG = [&](__half2* tt, int q) {  // 16 neighbors per chunk
#pragma unroll
      for (int j = 0; j < 8; j++) {
        int u = __builtin_nontemporal_load(&col[q + 2 * j + half]);
        tt[j] = gp[(size_t)u * 32 + dl];
      }
    };
    auto ACC = [&](const __half2* tt, float& sx, float& sy) {
#pragma unroll
      for (int j = 0; j < 8; j++) {
        float2 f = __half22float2(tt[j]);
        sx += f.x; sy += f.y;
      }
    };

    int rem = end - p;
    bool haveA = false;
    if (rem >= 16) { LG(tA, p); p += 16; rem -= 16; haveA = true; }
    while (rem >= 32) {
      LG(tB, p); ACC(tA, axA, ayA); p += 16; rem -= 16;
      LG(tA, p); ACC(tB, axB, ayB); p += 16; rem -= 16;
    }
    if (haveA) {
      if (rem >= 16) {
        LG(tB, p); ACC(tA, axA, ayA); p += 16; rem -= 16;
        ACC(tB, axB, ayB);
      } else {
        ACC(tA, axA, ayA);
      }
    }
    for (; rem >= 2; rem -= 2, p += 2) {
      int u = __builtin_nontemporal_load(&col[p + half]);
      float2 f = __half22float2(gp[(size_t)u * 32 + dl]);
      axA += f.x; ayA += f.y;
    }
    if (rem == 1 && half == 0) {
      int u = __builtin_nontemporal_load(&col[p]);
      float2 f = __half22float2(gp[(size_t)u * 32 + dl]);
      axA += f.x; ayA += f.y;
    }

    float ax = axA + axB, ay = ayA + ayB;
    ax += __shfl_xor(ax, 32);
    ay += __shfl_xor(ay, 32);

    if (half == 0) {
      float ox = fmaf(dv, ax, bias[dl * 2]);
      float oy = fmaf(dv, ay, bias[dl * 2 + 1]);
      if (RELU) { ox = fmaxf(ox, 0.f); oy = fmaxf(oy, 0.f); }
      if constexpr (sizeof(HOUT) == 2) {
        *(__half2*)&out[(size_t)v * 64 + dl * 2] = __float22half2_rn(make_float2(ox, oy));
      } else {
        float2 o; o.x = ox; o.y = oy;
        *(float2*)&out[(size_t)v * 64 + dl * 2] = o;
      }
    }
  }
}

// ---------------- launch ----------------

extern "C" void kernel_launch(void* const* d_in, const int* in_sizes, int n_in,
                              void* d_out, int out_size, void* d_ws, size_t ws_size,
                              hipStream_t stream) {
  const float* x  = (const float*)d_in[0];
  const int*   ei = (const int*)d_in[1];
  const float* W1 = (const float*)d_in[2];
  const float* b1 = (const float*)d_in[3];
  const float* W2 = (const float*)d_in[4];
  const float* b2 = (const float*)d_in[5];
  const float* W3 = (const float*)d_in[6];
  const float* b3 = (const float*)d_in[7];
  float* outp = (float*)d_out;

  const int N = in_sizes[0] / IN_DIM;   // 100000
  const int E = in_sizes[1] / 2;        // 3200000
  const int* src = ei;
  const int* dst = ei + E;
  const int NB = (N + NPB - 1) >> NPB_SHIFT;  // 391 buckets

  char* w = (char*)d_ws;
  auto take = [&](size_t bytes) {
    char* r = w;
    w += (bytes + 255) & ~size_t(255);
    return r;
  };
  float*  dis    = (float*)take((size_t)N * 4);
  int*    rowptr = (int*)take((size_t)(N + 1) * 4);
  int*    bsize  = (int*)take((size_t)NB * 4);
  int*    boff   = (int*)take((size_t)(NB + 1) * 4);
  int*    gcur   = (int*)take((size_t)NB * 4);
  int*    col    = (int*)take((size_t)E * 4);
  unsigned long long* bin = (unsigned long long*)take((size_t)E * 8);
  _Float16* Wp1  = (_Float16*)take((size_t)IN_DIM * HID_DIM * 2);
  _Float16* Wp2  = (_Float16*)take((size_t)HID_DIM * HID_DIM * 2);
  _Float16* Wp3  = (_Float16*)take((size_t)HID_DIM * OUT_DIM * 2);
  __half* gbuf   = (__half*)take((size_t)N * 128 * 2);  // GEMM out / gather buffer
  __half* bufH   = (__half*)take((size_t)N * 128 * 2);  // agg out (next GEMM A)

  const int cb = (E + CHUNK - 1) / CHUNK;
  hipLaunchKernelGGL(k_zero, dim3((NB + 255) / 256), dim3(256), 0, stream, bsize, NB);
  hipLaunchKernelGGL(k_hist, dim3(cb), dim3(256), 0, stream, dst, E, NB, bsize);
  hipLaunchKernelGGL(k_scanb, dim3(1), dim3(512), 0, stream, bsize, NB, E, boff, gcur);
  hipLaunchKernelGGL(k_binA, dim3(cb), dim3(256), 0, stream, src, dst, E, NB, gcur, bin);
  hipLaunchKernelGGL(k_passB, dim3(NB), dim3(256), 0, stream, bin, boff, NB, N, E, rowptr, dis, col);

  hipLaunchKernelGGL((k_packW<IN_DIM, HID_DIM>), dim3((IN_DIM * HID_DIM + 255) / 256), dim3(256), 0, stream, W1, Wp1);
  hipLaunchKernelGGL((k_packW<HID_DIM, HID_DIM>), dim3((HID_DIM * HID_DIM + 255) / 256), dim3(256), 0, stream, W2, Wp2);
  hipLaunchKernelGGL((k_packW<HID_DIM, OUT_DIM>), dim3((HID_DIM * OUT_DIM + 255) / 256), dim3(256), 0, stream, W3, Wp3);

  const int gb = (N + 63) / 64;
  const int ab = (N + 3) / 4;
  // layer 1: gbuf = fp16(dis*(x@W1)) -> agg+relu -> bufH (fp16)
  hipLaunchKernelGGL((k_gemm_mfma<IN_DIM, HID_DIM, float>), dim3(gb), dim3(256), 0, stream, x, Wp1, dis, gbuf, N);
  hipLaunchKernelGGL((k_agg<128, true, __half>), dim3(ab), dim3(256), 0, stream, gbuf, rowptr, col, dis, b1, bufH, N);
  // layer 2
  hipLaunchKernelGGL((k_gemm_mfma<HID_DIM, HID_DIM, __half>), dim3(gb), dim3(256), 0, stream, bufH, Wp2, dis, gbuf, N);
  hipLaunchKernelGGL((k_agg<128, true, __half>), dim3(ab), dim3(256), 0, stream, gbuf, rowptr, col, dis, b2, bufH, N);
  // layer 3 (no relu), 64-dim, fp32 straight to d_out
  hipLaunchKernelGGL((k_gemm_mfma<HID_DIM, OUT_DIM, __half>), dim3(gb), dim3(256), 0, stream, bufH, Wp3, dis, gbuf, N);
  hipLaunchKernelGGL((k_agg<64, false, float>), dim3(ab), dim3(256), 0, stream, gbuf, rowptr, col, dis, b3, outp, N);
}